// Round 5
// baseline (113.562 us; speedup 1.0000x reference)
//
#include <hip/hip_runtime.h>

#define BLK 512
#define MT 32            // mfma tile edge
#define IA 2             // A-frags per wave
#define IB 512           // rows per block = 8 waves * 32 * IA
#define JS 1024          // q points staged per block = whole j-range (no chunk loop)
#define SJ 16            // j-slices per (dir,b) -> grid (32,16,4) = 2048 blocks

typedef __attribute__((ext_vector_type(8))) short short8;
typedef __attribute__((ext_vector_type(16))) float f32x16;

__device__ __forceinline__ unsigned int fmap(float f) {
  unsigned int b = __float_as_uint(f);
  return (b & 0x80000000u) ? ~b : (b | 0x80000000u);
}
__device__ __forceinline__ float funmap(unsigned int u) {
  return __uint_as_float((u & 0x80000000u) ? (u ^ 0x80000000u) : ~u);
}
__device__ __forceinline__ unsigned short f2bf(float f) {
  unsigned int u = __float_as_uint(f);
  u += 0x7FFFu + ((u >> 16) & 1u);
  return (unsigned short)(u >> 16);
}
__device__ __forceinline__ float bf2f(unsigned short h) {
  return __uint_as_float(((unsigned int)h) << 16);
}
__device__ __forceinline__ unsigned int pk(unsigned short a, unsigned short b) {
  return (unsigned int)a | ((unsigned int)b << 16);
}

union FragU { uint4 u; short8 s; };

// Two MFMAs into VGPR destinations ("=&v" on the gfx950 unified file).
// s_nop 7,7,1 = 18 cyc covers MFMA D-write -> VALU-read (validated R11,
// absmax margin 0). R13: pipelining these away regresses. Keep.
#define MFMA2(d0, d1, a, b0, b1, c)                                    \
  asm("v_mfma_f32_32x32x16_bf16 %0, %2, %3, %5\n\t"                    \
      "v_mfma_f32_32x32x16_bf16 %1, %2, %4, %5\n\t"                    \
      "s_nop 7\n\t"                                                    \
      "s_nop 7\n\t"                                                    \
      "s_nop 1"                                                        \
      : "=&v"(d0), "=&v"(d1)                                           \
      : "v"(a), "v"(b0), "v"(b1), "v"(c))

// v_min3 with ALL operands pinned to arch VGPRs (R11: prevents AGPR
// allocation of run0/run1 and the a<->v copy tax).
#define MIN3(acc, x, y)                                                \
  asm("v_min3_f32 %0, %0, %1, %2" : "+v"(acc) : "v"(x), "v"(y))

// D_ij = |q_j|^2 - 2 p_i.q_j via split-bf16-compensated MFMA (k-slot layout
// verified R5-R11, absmax margin 0).
// R17: barrier-free main loop. R12-R16 established: idle is ~50% of SIMD
// time, not fixed by occupancy (R14/R15) nor LDS prefetch (R16); the one
// untested structural suspect is the 16-barrier chunk cadence that
// reconverges all waves every ~6.5K cycles. This version stages the block's
// ENTIRE j-range (JS=1024) once — ONE barrier per block, then 16 MFMA
// rounds of pure free-running compute. LDS 50KB -> 3 blocks/CU resident
// (6 waves/SIMD from 3 independent domains) + fresh blocks arrive staggered.
// Work is unchanged vs R12; downside bounded.
__global__ __launch_bounds__(BLK, 4) void cl_mfma(
    const float* __restrict__ A, const float* __restrict__ Bp,
    unsigned int* __restrict__ umin, float* __restrict__ outp,
    int N, int jslice, int Bn) {
  __shared__ uint4 sA[2][IB];   // A-vec halves [g][row]     16 KB
  __shared__ uint4 sB[2][JS];   // B-vec halves [g][point]   32 KB
  __shared__ float sNP[IB];     // |p|^2 per row              2 KB

  const int zi = blockIdx.z;
  const int dir = zi / Bn;
  const int b = zi - dir * Bn;
  const float* __restrict__ P = dir ? Bp : A;
  const float* __restrict__ Q = dir ? A : Bp;
  unsigned int* __restrict__ um = umin + ((size_t)dir * Bn + b) * N;

  const int t = threadIdx.x;

  // zero the scalar output here (stream order puts cl_reduce after all
  // cl_mfma blocks) — saves the out-memset launch node. (validated R16)
  if (blockIdx.x == 0 && blockIdx.y == 0 && blockIdx.z == 0 && t == 0)
    *outp = 0.0f;

  const int ib0 = blockIdx.x * IB;
  const int jbase = blockIdx.y * jslice;
  const size_t boff = (size_t)b * 3 * N;
  const unsigned short one = 0x3F80u;  // bf16(1.0)

  // ---- stage A-vectors + |p|^2 (one row per thread) ----
  {
    int i = ib0 + t;
    float x = P[boff + i], y = P[boff + N + i], zz = P[boff + 2 * N + i];
    float ax = -2.f * x, ay = -2.f * y, az = -2.f * zz;
    unsigned short hx = f2bf(ax), hy = f2bf(ay), hz = f2bf(az);
    unsigned short lx = f2bf(ax - bf2f(hx)), ly = f2bf(ay - bf2f(hy)),
                   lz = f2bf(az - bf2f(hz));
    sA[0][t] = make_uint4(pk(hx, hy), pk(hz, lx), pk(ly, lz), pk(hx, hy));
    sA[1][t] = make_uint4(pk(hz, lx), pk(ly, lz), pk(one, one), pk(one, 0));
    sNP[t] = fmaf(zz, zz, fmaf(y, y, x * x));
  }

  // ---- stage B-vectors (two q-points per thread), once ----
#pragma unroll
  for (int h = 0; h < 2; ++h) {
    int j = jbase + t + h * BLK;
    float qx = Q[boff + j];
    float qy = Q[boff + N + j];
    float qz = Q[boff + 2 * N + j];
    unsigned short hx = f2bf(qx), hy = f2bf(qy), hz = f2bf(qz);
    unsigned short lx = f2bf(qx - bf2f(hx)), ly = f2bf(qy - bf2f(hy)),
                   lz = f2bf(qz - bf2f(hz));
    float nq = fmaf(qz, qz, fmaf(qy, qy, qx * qx));
    unsigned short nh = f2bf(nq);
    float r1 = nq - bf2f(nh);
    unsigned short nm = f2bf(r1);
    unsigned short nl = f2bf(r1 - bf2f(nm));
    sB[0][t + h * BLK] = make_uint4(pk(hx, hy), pk(hz, hx), pk(hy, hz), pk(lx, ly));
    sB[1][t + h * BLK] = make_uint4(pk(lz, lx), pk(ly, lz), pk(nh, nm), pk(nl, 0));
  }

  __syncthreads();  // the ONLY barrier in the kernel

  const int w = t >> 6, l = t & 63, m = l & 31, g = l >> 5;
  FragU a0u, a1u;
  a0u.u = sA[g][w * (MT * IA) + m];        // rows w*64 + 0..31
  a1u.u = sA[g][w * (MT * IA) + MT + m];   // rows w*64 + 32..63
  const short8 af0 = a0u.s, af1 = a1u.s;
  const uint4* __restrict__ sBg = sB[g];

  float run0[16], run1[16];
  f32x16 zc;
#pragma unroll
  for (int r = 0; r < 16; ++r) { run0[r] = 3.0e38f; run1[r] = 3.0e38f; zc[r] = 0.0f; }

  // ---- barrier-free main loop: 16 rounds over 32 column tiles ----
#pragma unroll
  for (int jt = 0; jt < JS / MT; jt += 2) {
    FragU ba, bb;
    ba.u = sBg[(jt + 0) * MT + m];
    bb.u = sBg[(jt + 1) * MT + m];
    f32x16 d0, d1;
    MFMA2(d0, d1, af0, ba.s, bb.s, zc);
#pragma unroll
    for (int r = 0; r < 16; ++r) MIN3(run0[r], d0[r], d1[r]);
    f32x16 d2, d3;
    MFMA2(d2, d3, af1, ba.s, bb.s, zc);
#pragma unroll
    for (int r = 0; r < 16; ++r) MIN3(run1[r], d2[r], d3[r]);
  }

  // ---- epilogue: min across 32 cols, add |p|^2, atomicMin ----
  // C/D layout (m74/m101): col=lane&31, row=(reg&3)+8*(reg>>2)+4*(lane>>5)
#pragma unroll
  for (int r = 0; r < 16; ++r) {
    float v0 = run0[r], v1 = run1[r];
#pragma unroll
    for (int sh = 1; sh <= 16; sh <<= 1) {
      v0 = fminf(v0, __shfl_xor(v0, sh));
      v1 = fminf(v1, __shfl_xor(v1, sh));
    }
    if (m == 0) {
      int row = (r & 3) + 8 * (r >> 2) + 4 * g;
      int il0 = w * (MT * IA) + row;
      int il1 = il0 + MT;
      atomicMin(&um[ib0 + il0], fmap(v0 + sNP[il0]));
      atomicMin(&um[ib0 + il1], fmap(v1 + sNP[il1]));
    }
  }
}

// Parallel final reduce: u holds complete squared distances (256 KB).
__global__ __launch_bounds__(256) void cl_reduce(
    const unsigned int* __restrict__ u, float* __restrict__ out, int total) {
  const int t = threadIdx.x;
  const uint4* __restrict__ u4 = (const uint4*)u;
  const int n4 = total / 4;
  const int gid = blockIdx.x * 256 + t;
  const int gstride = gridDim.x * 256;
  double s = 0.0;
  for (int i = gid; i < n4; i += gstride) {
    uint4 v = u4[i];
    s += (double)funmap(v.x) + (double)funmap(v.y) +
         (double)funmap(v.z) + (double)funmap(v.w);
  }
  for (int off = 32; off > 0; off >>= 1) s += __shfl_down(s, off, 64);
  __shared__ double sw[4];
  if ((t & 63) == 0) sw[t >> 6] = s;
  __syncthreads();
  if (t == 0) {
    double tot = sw[0] + sw[1] + sw[2] + sw[3];
    atomicAdd(out, (float)(tot / (double)total));
  }
}

extern "C" void kernel_launch(void* const* d_in, const int* in_sizes, int n_in,
                              void* d_out, int out_size, void* d_ws, size_t ws_size,
                              hipStream_t stream) {
  const float* in_pc = (const float*)d_in[0];
  const float* tgt_pc = (const float*)d_in[1];
  const int B = 2, N = 16384;
  unsigned int* u = (unsigned int*)d_ws;  // [2][B][N] uints = 256 KB
  float* out = (float*)d_out;

  hipMemsetAsync(u, 0xFF, (size_t)2 * B * N * sizeof(unsigned int), stream);

  const int jslice = N / SJ;             // 1024
  dim3 grid(N / IB, SJ, 2 * B);          // (32,16,4) = 2048 blocks x 512 thr
  cl_mfma<<<grid, dim3(BLK), 0, stream>>>(in_pc, tgt_pc, u, out, N, jslice, B);

  const int total = 2 * B * N;
  cl_reduce<<<dim3(16), dim3(256), 0, stream>>>(u, out, total);
}

// Round 6
// 98.488 us; speedup vs baseline: 1.1531x; 1.1531x over previous
//
#include <hip/hip_runtime.h>

#define BLK 512
#define MT 32            // mfma tile edge
#define IA 2             // A-frags per wave
#define IB 512           // rows per block = 8 waves * 32 * IA
#define TJQ 512          // q points per LDS chunk
#define SJ 4             // j-slices per (dir,b) -> 512 blocks, one dispatch round

typedef __attribute__((ext_vector_type(8))) short short8;
typedef __attribute__((ext_vector_type(16))) float f32x16;

__device__ __forceinline__ unsigned int fmap(float f) {
  unsigned int b = __float_as_uint(f);
  return (b & 0x80000000u) ? ~b : (b | 0x80000000u);
}
__device__ __forceinline__ float funmap(unsigned int u) {
  return __uint_as_float((u & 0x80000000u) ? (u ^ 0x80000000u) : ~u);
}
__device__ __forceinline__ unsigned short f2bf(float f) {
  unsigned int u = __float_as_uint(f);
  u += 0x7FFFu + ((u >> 16) & 1u);
  return (unsigned short)(u >> 16);
}
__device__ __forceinline__ float bf2f(unsigned short h) {
  return __uint_as_float(((unsigned int)h) << 16);
}
__device__ __forceinline__ unsigned int pk(unsigned short a, unsigned short b) {
  return (unsigned int)a | ((unsigned int)b << 16);
}

union FragU { uint4 u; short8 s; };

// Two MFMAs into VGPR destinations ("=&v" on the gfx950 unified file).
// s_nop 7,7,1 = 18 cyc covers MFMA D-write -> VALU-read (validated R11,
// absmax margin 0). R13 (pipelining), R14/R15 (occupancy), R16 (LDS
// prefetch), R17 (barrier-free) all failed to beat this structure — the
// hot loop below is the validated 43.5us form and is left byte-identical.
#define MFMA2(d0, d1, a, b0, b1, c)                                    \
  asm("v_mfma_f32_32x32x16_bf16 %0, %2, %3, %5\n\t"                    \
      "v_mfma_f32_32x32x16_bf16 %1, %2, %4, %5\n\t"                    \
      "s_nop 7\n\t"                                                    \
      "s_nop 7\n\t"                                                    \
      "s_nop 1"                                                        \
      : "=&v"(d0), "=&v"(d1)                                           \
      : "v"(a), "v"(b0), "v"(b1), "v"(c))

// v_min3 with ALL operands pinned to arch VGPRs (R11: prevents AGPR
// allocation of run0/run1 and the a<->v copy tax).
#define MIN3(acc, x, y)                                                \
  asm("v_min3_f32 %0, %0, %1, %2" : "+v"(acc) : "v"(x), "v"(y))

// D_ij = |q_j|^2 - 2 p_i.q_j via split-bf16-compensated MFMA (k-slot layout
// verified R5-R11, absmax margin 0).
// R18: the hot loop is DONE being tuned (43.5us floor across R12-R17); this
// round attacks the other ~54us of wall (memset node + 16-block
// latency-bound reduce + launch gaps). Epilogue: each block's row-mins over
// its j-slice are complete partial minima -> plain float stores to a unique
// per-block slot pm[(dir,b)][by][i] (no init memset, no fmap, no atomicMin
// RMW). pmode is a wave-uniform runtime flag so the old atomic path remains
// as a workspace-size fallback without a second kernel instantiation.
__global__ __launch_bounds__(BLK, 4) void cl_mfma(
    const float* __restrict__ A, const float* __restrict__ Bp,
    unsigned int* __restrict__ umin, float* __restrict__ pm,
    float* __restrict__ outp, int N, int jslice, int Bn, int pmode) {
  __shared__ uint4 sA[2][IB];   // A-vec halves [g][row]
  __shared__ uint4 sB[2][TJQ];  // B-vec halves [g][point]
  __shared__ float sNP[IB];     // |p|^2 per row

  const int zi = blockIdx.z;
  const int dir = zi / Bn;
  const int b = zi - dir * Bn;
  const float* __restrict__ P = dir ? Bp : A;
  const float* __restrict__ Q = dir ? A : Bp;
  unsigned int* __restrict__ um = umin + ((size_t)dir * Bn + b) * N;
  const size_t pbase =
      ((size_t)(dir * Bn + b) * gridDim.y + blockIdx.y) * (size_t)N;

  const int t = threadIdx.x;

  // zero the scalar output here (stream order puts cl_reduce after all
  // cl_mfma blocks) — saves the out-memset launch node. (validated R16)
  if (blockIdx.x == 0 && blockIdx.y == 0 && blockIdx.z == 0 && t == 0)
    *outp = 0.0f;

  const int ib0 = blockIdx.x * IB;
  const int jbase = blockIdx.y * jslice;
  const size_t boff = (size_t)b * 3 * N;
  const unsigned short one = 0x3F80u;  // bf16(1.0)

  // ---- stage A-vectors + |p|^2 (once) ----
  {
    int i = ib0 + t;
    float x = P[boff + i], y = P[boff + N + i], zz = P[boff + 2 * N + i];
    float ax = -2.f * x, ay = -2.f * y, az = -2.f * zz;
    unsigned short hx = f2bf(ax), hy = f2bf(ay), hz = f2bf(az);
    unsigned short lx = f2bf(ax - bf2f(hx)), ly = f2bf(ay - bf2f(hy)),
                   lz = f2bf(az - bf2f(hz));
    sA[0][t] = make_uint4(pk(hx, hy), pk(hz, lx), pk(ly, lz), pk(hx, hy));
    sA[1][t] = make_uint4(pk(hz, lx), pk(ly, lz), pk(one, one), pk(one, 0));
    sNP[t] = fmaf(zz, zz, fmaf(y, y, x * x));
  }
  __syncthreads();

  const int w = t >> 6, l = t & 63, m = l & 31, g = l >> 5;
  FragU a0u, a1u;
  a0u.u = sA[g][w * (MT * IA) + m];        // rows w*64 + 0..31
  a1u.u = sA[g][w * (MT * IA) + MT + m];   // rows w*64 + 32..63
  const short8 af0 = a0u.s, af1 = a1u.s;
  const uint4* __restrict__ sBg = sB[g];

  float run0[16], run1[16];
  f32x16 zc;
#pragma unroll
  for (int r = 0; r < 16; ++r) { run0[r] = 3.0e38f; run1[r] = 3.0e38f; zc[r] = 0.0f; }

  const int nch = jslice / TJQ;  // 8
  float qx = Q[boff + jbase + t];
  float qy = Q[boff + N + jbase + t];
  float qz = Q[boff + 2 * N + jbase + t];

  for (int ch = 0; ch < nch; ++ch) {
    unsigned short hx = f2bf(qx), hy = f2bf(qy), hz = f2bf(qz);
    unsigned short lx = f2bf(qx - bf2f(hx)), ly = f2bf(qy - bf2f(hy)),
                   lz = f2bf(qz - bf2f(hz));
    float nq = fmaf(qz, qz, fmaf(qy, qy, qx * qx));
    unsigned short nh = f2bf(nq);
    float r1 = nq - bf2f(nh);
    unsigned short nm = f2bf(r1);
    unsigned short nl = f2bf(r1 - bf2f(nm));
    uint4 b0s = make_uint4(pk(hx, hy), pk(hz, hx), pk(hy, hz), pk(lx, ly));
    uint4 b1s = make_uint4(pk(lz, lx), pk(ly, lz), pk(nh, nm), pk(nl, 0));

    __syncthreads();  // previous chunk fully consumed
    sB[0][t] = b0s;
    sB[1][t] = b1s;
    {  // prefetch next chunk's q
      int jn = (ch + 1 < nch) ? (jbase + (ch + 1) * TJQ + t) : (jbase + t);
      qx = Q[boff + jn];
      qy = Q[boff + N + jn];
      qz = Q[boff + 2 * N + jn];
    }
    __syncthreads();

    // 1-pair register double-buffer (R16; neutral but validated).
    FragU ba, bb, na, nb;
    ba.u = sBg[m];
    bb.u = sBg[MT + m];
    na = ba; nb = bb;
#pragma unroll
    for (int jt = 0; jt < TJQ / MT; jt += 2) {
      if (jt + 2 < TJQ / MT) {
        na.u = sBg[(jt + 2) * MT + m];
        nb.u = sBg[(jt + 3) * MT + m];
      }
      f32x16 d0, d1;
      MFMA2(d0, d1, af0, ba.s, bb.s, zc);
#pragma unroll
      for (int r = 0; r < 16; ++r) MIN3(run0[r], d0[r], d1[r]);
      f32x16 d2, d3;
      MFMA2(d2, d3, af1, ba.s, bb.s, zc);
#pragma unroll
      for (int r = 0; r < 16; ++r) MIN3(run1[r], d2[r], d3[r]);
      ba = na; bb = nb;
    }
  }

  // ---- epilogue: min across 32 cols, add |p|^2, store/atomicMin ----
  // C/D layout (m74/m101): col=lane&31, row=(reg&3)+8*(reg>>2)+4*(lane>>5)
#pragma unroll
  for (int r = 0; r < 16; ++r) {
    float v0 = run0[r], v1 = run1[r];
#pragma unroll
    for (int sh = 1; sh <= 16; sh <<= 1) {
      v0 = fminf(v0, __shfl_xor(v0, sh));
      v1 = fminf(v1, __shfl_xor(v1, sh));
    }
    if (m == 0) {
      int row = (r & 3) + 8 * (r >> 2) + 4 * g;
      int il0 = w * (MT * IA) + row;
      int il1 = il0 + MT;
      if (pmode) {  // wave-uniform; per-block-unique slots, no init needed
        pm[pbase + ib0 + il0] = v0 + sNP[il0];
        pm[pbase + ib0 + il1] = v1 + sNP[il1];
      } else {
        atomicMin(&um[ib0 + il0], fmap(v0 + sNP[il0]));
        atomicMin(&um[ib0 + il1], fmap(v1 + sNP[il1]));
      }
    }
  }
}

// R18 wide reduce: min over the SJ per-slice partials, then mean.
// 64 blocks (vs old 16) so the tail isn't latency-bound on 6% of the GPU.
__global__ __launch_bounds__(256) void cl_reduce_p(
    const float* __restrict__ pm, float* __restrict__ out,
    int N, int sj, int rows) {
  const int t = threadIdx.x;
  const int gid = blockIdx.x * 256 + t;
  const int gstride = gridDim.x * 256;
  double s = 0.0;
  for (int idx = gid; idx < rows; idx += gstride) {
    int rr = idx / N;
    int i = idx - rr * N;
    const float* p = pm + ((size_t)rr * sj) * N + i;
    float mv = p[0];
    for (int by = 1; by < sj; ++by) mv = fminf(mv, p[(size_t)by * N]);
    s += (double)mv;
  }
  for (int off = 32; off > 0; off >>= 1) s += __shfl_down(s, off, 64);
  __shared__ double sw[4];
  if ((t & 63) == 0) sw[t >> 6] = s;
  __syncthreads();
  if (t == 0) {
    double tot = sw[0] + sw[1] + sw[2] + sw[3];
    atomicAdd(out, (float)(tot / (double)rows));
  }
}

// Fallback reduce (umin/fmap path), kept for small-workspace case.
__global__ __launch_bounds__(256) void cl_reduce(
    const unsigned int* __restrict__ u, float* __restrict__ out, int total) {
  const int t = threadIdx.x;
  const uint4* __restrict__ u4 = (const uint4*)u;
  const int n4 = total / 4;
  const int gid = blockIdx.x * 256 + t;
  const int gstride = gridDim.x * 256;
  double s = 0.0;
  for (int i = gid; i < n4; i += gstride) {
    uint4 v = u4[i];
    s += (double)funmap(v.x) + (double)funmap(v.y) +
         (double)funmap(v.z) + (double)funmap(v.w);
  }
  for (int off = 32; off > 0; off >>= 1) s += __shfl_down(s, off, 64);
  __shared__ double sw[4];
  if ((t & 63) == 0) sw[t >> 6] = s;
  __syncthreads();
  if (t == 0) {
    double tot = sw[0] + sw[1] + sw[2] + sw[3];
    atomicAdd(out, (float)(tot / (double)total));
  }
}

extern "C" void kernel_launch(void* const* d_in, const int* in_sizes, int n_in,
                              void* d_out, int out_size, void* d_ws, size_t ws_size,
                              hipStream_t stream) {
  const float* in_pc = (const float*)d_in[0];
  const float* tgt_pc = (const float*)d_in[1];
  const int B = 2, N = 16384;
  float* out = (float*)d_out;
  const int jslice = N / SJ;             // 4096
  dim3 grid(N / IB, SJ, 2 * B);          // (32,4,4) = 512 blocks x 512 thr

  const size_t need = (size_t)2 * B * SJ * N * sizeof(float);  // 1 MB
  if (ws_size >= need) {
    // Partial-store path: 2 launches, no memset, no atomics.
    float* pm = (float*)d_ws;            // [2*B][SJ][N] floats
    cl_mfma<<<grid, dim3(BLK), 0, stream>>>(in_pc, tgt_pc, (unsigned int*)d_ws,
                                            pm, out, N, jslice, B, 1);
    cl_reduce_p<<<dim3(64), dim3(256), 0, stream>>>(pm, out, N, SJ, 2 * B * N);
  } else {
    // Fallback: atomicMin into fmap-mapped uints (256 KB).
    unsigned int* u = (unsigned int*)d_ws;
    hipMemsetAsync(u, 0xFF, (size_t)2 * B * N * sizeof(unsigned int), stream);
    cl_mfma<<<grid, dim3(BLK), 0, stream>>>(in_pc, tgt_pc, u, (float*)d_ws,
                                            out, N, jslice, B, 0);
    cl_reduce<<<dim3(64), dim3(256), 0, stream>>>(u, out, 2 * B * N);
  }
}